// Round 6
// baseline (1958.964 us; speedup 1.0000x reference)
//
#include <hip/hip_runtime.h>
#include <math.h>

#define S_LEN 1024
#define BATCH 2048
#define MTILE 8
#define HID   128
#define NBLK  (BATCH / MTILE)   // 256 blocks -> every CU active
#define INV2048 (1.0f / 2048.0f)
#define NLOG2E (-1.44269504088896341f)   // folded into M/A gate weights

// ws layout, offsets in _Float16 elements. Ten [128][128] hi/lo weight
// arrays; M/A-gate weights are pre-scaled by -log2(e) so the sigmoid is
// rcp(1 + exp2(pre)) with a bare v_exp_f32.
#define H_M1H 0
#define H_M1L 16384
#define H_MSH 32768
#define H_MSL 49152
#define H_ASH 65536
#define H_ASL 81920
#define H_WMH 98304      // [128][128] WtauM[:,128:256] hi (scaled)
#define H_WML 114688
#define H_WBH 131072     // [128][128] WtauAdp[:,128:256] hi (scaled)
#define H_WBL 147456
// f32 ext-coefficient table: 9 arrays of [128] floats, gate-major:
// idx (gate*3 + col)*128 + h ; gate 0=d,1=M,2=A ; col 0=bias,1=x0,2=x1.
// M/A rows pre-scaled by -log2(e); d row unscaled.
#define F_EXT      81920     // float index (== 163840 halfs)
#define OFF_PART_F 83072     // float index of per-block partials [256]

typedef _Float16 half8 __attribute__((ext_vector_type(8)));
typedef _Float16 half4 __attribute__((ext_vector_type(4)));
typedef _Float16 half2h __attribute__((ext_vector_type(2)));
typedef float floatx4 __attribute__((ext_vector_type(4)));
typedef float floatx2 __attribute__((ext_vector_type(2)));

#define MFMA(a, b, c) __builtin_amdgcn_mfma_f32_16x16x32_f16((a), (b), (c), 0, 0, 0)

__device__ __forceinline__ void put_hl(_Float16* ws, int hiBase, int loBase,
                                       int idx, float v) {
  _Float16 hi = (_Float16)v;
  ws[hiBase + idx] = hi;
  ws[loBase + idx] = (_Float16)((v - (float)hi) * 2048.0f);
}

// DPP row_ror:8 == xor-8 within each 16-lane row (8 = half the 16-ring).
// VALU pipe instead of the over-subscribed LDS pipe.
__device__ __forceinline__ float dpp_xor8(float v) {
  int sw = __builtin_amdgcn_update_dpp(0, __float_as_int(v),
                                       0x128 /*row_ror:8*/, 0xF, 0xF, true);
  return __int_as_float(sw);
}

// u-scheme fold for gates with a cross term (M, A): pre-combine
// u_r = hi_r + lo_r/2048 on the natural side, then one exchange each way.
// Lane c finishes r=0,1; lane c+8 finishes r=2,3.
__device__ __forceinline__ void fold_u(floatx4 g1, floatx4 g2, bool side,
                                       float out[2]) {
  float u0 = g1[0] + g2[0] * INV2048;
  float u1 = g1[1] + g2[1] * INV2048;
  float u2 = g1[2] + g2[2] * INV2048;
  float u3 = g1[3] + g2[3] * INV2048;
  float t0 = dpp_xor8(g1[0]);   // act receives cross_0
  float t1 = dpp_xor8(g1[1]);
  float t2 = dpp_xor8(u2);      // side receives act's u2
  float t3 = dpp_xor8(u3);
  float base0 = side ? t2 : u0, add0 = side ? g1[2] : t0;
  float base1 = side ? t3 : u1, add1 = side ? g1[3] : t1;
  out[0] = base0 + add0 * INV2048;
  out[1] = base1 + add1 * INV2048;
}

// d gate: spk cols 8-15 are exactly 0 -> cross terms vanish on both sides.
__device__ __forceinline__ void fold_d(floatx4 g1, floatx4 g2, bool side,
                                       float out[2]) {
  float u0 = g1[0] + g2[0] * INV2048;
  float u1 = g1[1] + g2[1] * INV2048;
  float u2 = g1[2] + g2[2] * INV2048;
  float u3 = g1[3] + g2[3] * INV2048;
  float t2 = dpp_xor8(u2);
  float t3 = dpp_xor8(u3);
  out[0] = side ? t2 : u0;
  out[1] = side ? t3 : u1;
}

// ---- prep: fold dense->tau coupling into f16 hi/lo fragment arrays, plus
// the f32 ext-coefficient table. M/A-gate paths pre-scaled by -log2(e).
__global__ __launch_bounds__(192) void prep(
    const float* __restrict__ W1x, const float* __restrict__ b1x,
    const float* __restrict__ WtauM, const float* __restrict__ btauM,
    const float* __restrict__ WtauAdp, const float* __restrict__ btauAdp,
    _Float16* __restrict__ ws) {
  const int h = blockIdx.x, k = threadIdx.x;
  if (k >= 131) return;
  if (k < 128) {
    float w1 = W1x[h * 130 + 2 + k];
    float s1 = 0.f, s2 = 0.f;
    for (int d = 0; d < 128; ++d) {
      float wd = W1x[d * 130 + 2 + k];
      s1 += WtauM[h * 256 + d] * wd;
      s2 += WtauAdp[h * 256 + d] * wd;
    }
    put_hl(ws, H_M1H, H_M1L, h * 128 + k, w1);
    put_hl(ws, H_MSH, H_MSL, h * 128 + k, s1 * NLOG2E);
    put_hl(ws, H_ASH, H_ASL, h * 128 + k, s2 * NLOG2E);
    put_hl(ws, H_WMH, H_WML, h * 128 + k, WtauM[h * 256 + 128 + k] * NLOG2E);
    put_hl(ws, H_WBH, H_WBL, h * 128 + k, WtauAdp[h * 256 + 128 + k] * NLOG2E);
  } else {
    const int col = k - 128;   // 0: bias, 1: x0-coef, 2: x1-coef
    float m1v = (col == 0) ? b1x[h] : W1x[h * 130 + (col - 1)];
    float sm = 0.f, sa = 0.f;
    for (int d = 0; d < 128; ++d) {
      float cv = (col == 0) ? b1x[d] : W1x[d * 130 + (col - 1)];
      sm += WtauM[h * 256 + d] * cv;
      sa += WtauAdp[h * 256 + d] * cv;
    }
    if (col == 0) { sm += btauM[h]; sa += btauAdp[h]; }
    float* EXTF = (float*)ws + F_EXT;
    EXTF[(0 * 3 + col) * 128 + h] = m1v;
    EXTF[(1 * 3 + col) * 128 + h] = sm * NLOG2E;
    EXTF[(2 * 3 + col) * 128 + h] = sa * NLOG2E;
  }
}

// State slabs. mem/bbp per k-chunk: 1 KB, half-index (q'*16+n')*8+j holds
// B[k=f*32+q'*8+j][n']; n'=0..7 hi, n'=8..15 lo(x2048). spk is PACKED to the
// 8 real cols (spike is exact in f16, no lo) -> 512 B/chunk, fully
// overwritten every step. Side lanes broadcast-read zero16 for S.
struct SLds {
  _Float16 spk[2][4][256];
  _Float16 zero16[8];           // 16 B of zeros, same-address broadcast read
  _Float16 mem[2][4][512];
  _Float16 bbp[2][4][512];
  float red[8][8];
  float red2[8];
};

__global__ __launch_bounds__(512, 2) void snn_main(
    const float* __restrict__ x, const float* __restrict__ y,
    const float* __restrict__ h0m, const float* __restrict__ h0s,
    const float* __restrict__ h0b,
    const float* __restrict__ Wlin, const float* __restrict__ blin,
    const _Float16* __restrict__ W, float* __restrict__ wsout) {
  __shared__ SLds L;

  const int tid  = threadIdx.x;
  const int w    = tid >> 6;      // wave 0..7, owns h-slice [16w, 16w+16)
  const int lane = tid & 63;
  const int c    = lane & 15;     // A-frag m / B-frag n / C col
  const int q    = lane >> 4;
  const int cc   = c & 7;         // batch column within the tile
  const int bbase = blockIdx.x * MTILE;
  const bool act  = (c < 8);
  const bool side = !act;         // side lanes own neurons r=2,3

  // ---- Register-resident A-frag weights (MFMA-only -> AGPR side)
  half8 m1h[4], m1l[4], msh[4], msl[4], ash[4], asl[4];
  half8 wmh[4], wml[4], wbh[4], wbl[4];
  {
    const int hA = w * 16 + c;
#pragma unroll
    for (int f = 0; f < 4; ++f) {
      const int o = hA * 128 + f * 32 + q * 8;
      m1h[f] = *(const half8*)&W[H_M1H + o];
      m1l[f] = *(const half8*)&W[H_M1L + o];
      msh[f] = *(const half8*)&W[H_MSH + o];
      msl[f] = *(const half8*)&W[H_MSL + o];
      ash[f] = *(const half8*)&W[H_ASH + o];
      asl[f] = *(const half8*)&W[H_ASL + o];
      wmh[f] = *(const half8*)&W[H_WMH + o];
      wml[f] = *(const half8*)&W[H_WML + o];
      wbh[f] = *(const half8*)&W[H_WBH + o];
      wbl[f] = *(const half8*)&W[H_WBL + o];
    }
  }

  if (tid == 0) {   // 16 B zero block for c>=8 broadcast S reads
    *(half8*)&L.zero16[0] = half8{0, 0, 0, 0, 0, 0, 0, 0};
  }

  // ---- f32 ext coefficients for this lane's 2 neurons (h0i, h0i+1)
  const int h0i = w * 16 + q * 4 + (side ? 2 : 0);
  const float* CF = (const float*)W + F_EXT;
  floatx2 cd0 = *(const floatx2*)&CF[0 * 128 + h0i];
  floatx2 cd1 = *(const floatx2*)&CF[1 * 128 + h0i];
  floatx2 cd2 = *(const floatx2*)&CF[2 * 128 + h0i];
  floatx2 cm0 = *(const floatx2*)&CF[3 * 128 + h0i];
  floatx2 cm1 = *(const floatx2*)&CF[4 * 128 + h0i];
  floatx2 cm2 = *(const floatx2*)&CF[5 * 128 + h0i];
  floatx2 ca0 = *(const floatx2*)&CF[6 * 128 + h0i];
  floatx2 ca1 = *(const floatx2*)&CF[7 * 128 + h0i];
  floatx2 ca2 = *(const floatx2*)&CF[8 * 128 + h0i];

  // ---- Per-lane recurrent state: EVERY lane owns 2 neurons.
  float memv[2], spk[2], bb[2];
  {
    const int gi = (bbase + cc) * HID + h0i;
    float2 tm = *(const float2*)&h0m[gi];
    float2 ts = *(const float2*)&h0s[gi];
    float2 tb = *(const float2*)&h0b[gi];
    memv[0] = tm.x; memv[1] = tm.y;
    spk[0]  = ts.x; spk[1]  = ts.y;
    bb[0]   = tb.x; bb[1]   = tb.y;
  }

  // State value (h = w*16+q*4+side*2+rr) enters GEMM2 as B[k=h][n]:
  // chunk fW = w>>1, granule qp = (w&1)*2 + (q>>1), j = (q&1)*4 + side*2 + rr.
  const int fW  = w >> 1;
  const int qp  = (w & 1) * 2 + (q >> 1);
  const int jo  = (q & 1) * 4 + (side ? 2 : 0);
  const int wiH = (qp * 16 + cc) * 8 + jo;        // mem/bbp hi (n'=cc)
  const int wiL = wiH + 64;                       // mem/bbp lo (n'=cc+8)
  const int wiS = (qp * 8 + cc) * 8 + jo;         // packed spk
  const int ri  = lane * 8;                       // mem/bbp read (identity)
  const _Float16* spkB0 = act ? &L.spk[0][0][(q * 8 + cc) * 8] : L.zero16;
  const _Float16* spkB1 = act ? &L.spk[1][0][(q * 8 + cc) * 8] : L.zero16;
  const int spkStep = act ? 256 : 0;

  {   // initial state into buf 0 (all lanes, 2 values each)
    half2h ps2, mh2, ml2, bh2, bl2;
#pragma unroll
    for (int rr = 0; rr < 2; ++rr) {
      ps2[rr] = (_Float16)spk[rr];
      float v = memv[rr]; _Float16 hi = (_Float16)v;
      mh2[rr] = hi; ml2[rr] = (_Float16)((v - (float)hi) * 2048.0f);
      v = bb[rr]; hi = (_Float16)v;
      bh2[rr] = hi; bl2[rr] = (_Float16)((v - (float)hi) * 2048.0f);
    }
    *(half2h*)&L.spk[0][fW][wiS] = ps2;
    *(half2h*)&L.mem[0][fW][wiH] = mh2; *(half2h*)&L.mem[0][fW][wiL] = ml2;
    *(half2h*)&L.bbp[0][fW][wiH] = bh2; *(half2h*)&L.bbp[0][fW][wiL] = bl2;
  }
  __syncthreads();

  // Per-lane x stream for batch bbase+cc, prefetched one step ahead.
  const float* xb = x + (size_t)(bbase + cc) * 2;
  float2 xv = *(const float2*)xb;   // x at t=0

#pragma unroll 1
  for (int t = 0; t < S_LEN; ++t) {
    const int p = t & 1, pn = p ^ 1;
    const size_t tn = (t + 1 < S_LEN) ? (size_t)(t + 1) : (size_t)t;
    float2 xnx = *(const float2*)(xb + tn * (size_t)(BATCH * 2));  // prefetch

    const _Float16* sB = p ? spkB1 : spkB0;

    // Split the 8-deep M/A accumulator chains into two 4-deep halves
    // (10 independent MFMA dep-chains total) to remove dep-latency bubbles.
    floatx4 d1 = {0.f,0.f,0.f,0.f}, d2 = {0.f,0.f,0.f,0.f};
    floatx4 m1A = {0.f,0.f,0.f,0.f}, m1B = {0.f,0.f,0.f,0.f};
    floatx4 m2A = {0.f,0.f,0.f,0.f}, m2B = {0.f,0.f,0.f,0.f};
    floatx4 a1A = {0.f,0.f,0.f,0.f}, a1B = {0.f,0.f,0.f,0.f};
    floatx4 a2A = {0.f,0.f,0.f,0.f}, a2B = {0.f,0.f,0.f,0.f};

#pragma unroll
    for (int f = 0; f < 2; ++f) {
      half8 S = *(const half8*)&sB[f * spkStep];
      half8 M = *(const half8*)&L.mem[p][f][ri];
      half8 B = *(const half8*)&L.bbp[p][f][ri];
      d1  = MFMA(m1h[f], S, d1);
      d2  = MFMA(m1l[f], S, d2);
      m1A = MFMA(msh[f], S, m1A);
      m1A = MFMA(wmh[f], M, m1A);
      m2A = MFMA(msl[f], S, m2A);
      m2A = MFMA(wml[f], M, m2A);
      a1A = MFMA(ash[f], S, a1A);
      a1A = MFMA(wbh[f], B, a1A);
      a2A = MFMA(asl[f], S, a2A);
      a2A = MFMA(wbl[f], B, a2A);
    }
#pragma unroll
    for (int f = 2; f < 4; ++f) {
      half8 S = *(const half8*)&sB[f * spkStep];
      half8 M = *(const half8*)&L.mem[p][f][ri];
      half8 B = *(const half8*)&L.bbp[p][f][ri];
      d1  = MFMA(m1h[f], S, d1);
      d2  = MFMA(m1l[f], S, d2);
      m1B = MFMA(msh[f], S, m1B);
      m1B = MFMA(wmh[f], M, m1B);
      m2B = MFMA(msl[f], S, m2B);
      m2B = MFMA(wml[f], M, m2B);
      a1B = MFMA(ash[f], S, a1B);
      a1B = MFMA(wbh[f], B, a1B);
      a2B = MFMA(asl[f], S, a2B);
      a2B = MFMA(wbl[f], B, a2B);
    }
    floatx4 m1 = m1A + m1B, m2 = m2A + m2B;
    floatx4 a1 = a1A + a1B, a2 = a2A + a2B;

    const float xc0 = xv.x, xc1 = xv.y;

    // M gate first: its exp2 issues while the a/d folds run on the VALU.
    float preM[2], preA[2], den[2];
    fold_u(m1, m2, side, preM);
    float pM0 = preM[0] + cm0[0] + cm1[0] * xc0 + cm2[0] * xc1;
    float pM1 = preM[1] + cm0[1] + cm1[1] * xc0 + cm2[1] * xc1;
    float eM0 = __builtin_amdgcn_exp2f(pM0);   // weights pre-scaled by -log2e
    float eM1 = __builtin_amdgcn_exp2f(pM1);
    fold_u(a1, a2, side, preA);
    float pA0 = preA[0] + ca0[0] + ca1[0] * xc0 + ca2[0] * xc1;
    float pA1 = preA[1] + ca0[1] + ca1[1] * xc0 + ca2[1] * xc1;
    float eA0 = __builtin_amdgcn_exp2f(pA0);
    float eA1 = __builtin_amdgcn_exp2f(pA1);
    fold_d(d1, d2, side, den);

    float tM[2] = { __builtin_amdgcn_rcpf(1.0f + eM0),
                    __builtin_amdgcn_rcpf(1.0f + eM1) };
    float tA[2] = { __builtin_amdgcn_rcpf(1.0f + eA0),
                    __builtin_amdgcn_rcpf(1.0f + eA1) };

    // ---- Elementwise update: 2 real neurons per lane (64 lanes busy).
    half2h ps2, mh2, ml2, bh2, bl2;
#pragma unroll
    for (int rr = 0; rr < 2; ++rr) {
      float dv = den[rr] + cd0[rr] + cd1[rr] * xc0 + cd2[rr] * xc1;
      bb[rr] = tA[rr] * bb[rr] + (1.0f - tA[rr]) * spk[rr];
      float Bth = 0.01f + 1.8f * bb[rr];
      memv[rr] = memv[rr] * tM[rr] + (1.0f - tM[rr]) * dv - Bth * spk[rr];
      spk[rr] = (memv[rr] - Bth) > 0.0f ? 1.0f : 0.0f;
      ps2[rr] = (_Float16)spk[rr];
      float v = bb[rr]; _Float16 hi = (_Float16)v;
      bh2[rr] = hi; bl2[rr] = (_Float16)((v - (float)hi) * 2048.0f);
      v = memv[rr]; hi = (_Float16)v;
      mh2[rr] = hi; ml2[rr] = (_Float16)((v - (float)hi) * 2048.0f);
    }
    // bbp/spk stores first: start the lgkm drain while mem pack retires.
    *(half2h*)&L.bbp[pn][fW][wiH] = bh2; *(half2h*)&L.bbp[pn][fW][wiL] = bl2;
    *(half2h*)&L.spk[pn][fW][wiS] = ps2;
    *(half2h*)&L.mem[pn][fW][wiH] = mh2; *(half2h*)&L.mem[pn][fW][wiL] = ml2;

    xv = xnx;
    __syncthreads();
  }

  // ---- Readout: out[b] = mem[b,:] @ Wlin + blin; per-block loss partial
  float part = memv[0] * Wlin[h0i] + memv[1] * Wlin[h0i + 1];
  part += __shfl_xor(part, 8);    // sum over side
  part += __shfl_xor(part, 16);   // sum over q
  part += __shfl_xor(part, 32);
  if (lane < 8) L.red[w][c] = part;
  __syncthreads();
  if (tid < 8) {
    float s = 0.0f;
#pragma unroll
    for (int ww = 0; ww < 8; ++ww) s += L.red[ww][tid];
    float out = s + blin[0];
    float d = out - y[bbase + tid];
    L.red2[tid] = d * d;
  }
  __syncthreads();
  if (tid == 0) {
    float s = 0.0f;
#pragma unroll
    for (int m = 0; m < MTILE; ++m) s += L.red2[m];
    wsout[blockIdx.x] = s;
  }
}

__global__ __launch_bounds__(256) void final_reduce(const float* __restrict__ part,
                                                    float* __restrict__ out) {
  __shared__ float sh[256];
  int t = threadIdx.x;
  sh[t] = part[t];
  __syncthreads();
  for (int s = 128; s > 0; s >>= 1) {
    if (t < s) sh[t] += sh[t + s];
    __syncthreads();
  }
  if (t == 0) out[0] = sh[0] * (1.0f / (float)BATCH);
}

extern "C" void kernel_launch(void* const* d_in, const int* in_sizes, int n_in,
                              void* d_out, int out_size, void* d_ws, size_t ws_size,
                              hipStream_t stream) {
  const float* x       = (const float*)d_in[0];
  const float* y       = (const float*)d_in[1];
  const float* h0m     = (const float*)d_in[2];
  const float* h0s     = (const float*)d_in[3];
  const float* h0b     = (const float*)d_in[4];
  const float* W1x     = (const float*)d_in[5];
  const float* b1x     = (const float*)d_in[6];
  const float* WtauM   = (const float*)d_in[7];
  const float* btauM   = (const float*)d_in[8];
  const float* WtauAdp = (const float*)d_in[9];
  const float* btauAdp = (const float*)d_in[10];
  const float* Wlin    = (const float*)d_in[11];
  const float* blin    = (const float*)d_in[12];
  _Float16* wsf16 = (_Float16*)d_ws;
  float* wspart = (float*)d_ws + OFF_PART_F;

  prep<<<128, 192, 0, stream>>>(W1x, b1x, WtauM, btauM, WtauAdp, btauAdp, wsf16);
  snn_main<<<NBLK, 512, 0, stream>>>(x, y, h0m, h0s, h0b, Wlin, blin,
                                     wsf16, wspart);
  final_reduce<<<1, 256, 0, stream>>>(wspart, (float*)d_out);
}

// Round 7
// 1525.020 us; speedup vs baseline: 1.2845x; 1.2845x over previous
//
#include <hip/hip_runtime.h>
#include <math.h>

#define S_LEN 1024
#define BATCH 2048
#define MTILE 8
#define HID   128
#define NBLK  (BATCH / MTILE)   // 256 blocks -> every CU active
#define INV2048 (1.0f / 2048.0f)
#define NLOG2E (-1.44269504088896341f)   // folded into M/A gate weights

// ws layout, offsets in _Float16 elements. Ten [128][128] hi/lo weight
// arrays; M/A-gate weights are pre-scaled by -log2(e) so the sigmoid is
// rcp(1 + exp2(pre)) with a bare v_exp_f32.
#define H_M1H 0
#define H_M1L 16384
#define H_MSH 32768
#define H_MSL 49152
#define H_ASH 65536
#define H_ASL 81920
#define H_WMH 98304      // [128][128] WtauM[:,128:256] hi (scaled)
#define H_WML 114688
#define H_WBH 131072     // [128][128] WtauAdp[:,128:256] hi (scaled)
#define H_WBL 147456
// f32 ext-coefficient table: 9 arrays of [128] floats, gate-major:
// idx (gate*3 + col)*128 + h ; gate 0=d,1=M,2=A ; col 0=bias,1=x0,2=x1.
// M/A rows pre-scaled by -log2(e); d row unscaled.
#define F_EXT      81920     // float index (== 163840 halfs)
#define OFF_PART_F 83072     // float index of per-block partials [256]

typedef _Float16 half8 __attribute__((ext_vector_type(8)));
typedef _Float16 half4 __attribute__((ext_vector_type(4)));
typedef _Float16 half2h __attribute__((ext_vector_type(2)));
typedef float floatx4 __attribute__((ext_vector_type(4)));
typedef float floatx2 __attribute__((ext_vector_type(2)));

#define MFMA(a, b, c) __builtin_amdgcn_mfma_f32_16x16x32_f16((a), (b), (c), 0, 0, 0)

__device__ __forceinline__ void put_hl(_Float16* ws, int hiBase, int loBase,
                                       int idx, float v) {
  _Float16 hi = (_Float16)v;
  ws[hiBase + idx] = hi;
  ws[loBase + idx] = (_Float16)((v - (float)hi) * 2048.0f);
}

// DPP row_ror:8 == xor-8 within each 16-lane row (8 = half the 16-ring).
// VALU pipe instead of the over-subscribed LDS pipe.
__device__ __forceinline__ float dpp_xor8(float v) {
  int sw = __builtin_amdgcn_update_dpp(0, __float_as_int(v),
                                       0x128 /*row_ror:8*/, 0xF, 0xF, true);
  return __int_as_float(sw);
}

// u-scheme fold for gates with a cross term (M, A): pre-combine
// u_r = hi_r + lo_r/2048 on the natural side, then one exchange each way.
// Lane c finishes r=0,1; lane c+8 finishes r=2,3.
__device__ __forceinline__ void fold_u(floatx4 g1, floatx4 g2, bool side,
                                       float out[2]) {
  float u0 = g1[0] + g2[0] * INV2048;
  float u1 = g1[1] + g2[1] * INV2048;
  float u2 = g1[2] + g2[2] * INV2048;
  float u3 = g1[3] + g2[3] * INV2048;
  float t0 = dpp_xor8(g1[0]);   // act receives cross_0
  float t1 = dpp_xor8(g1[1]);
  float t2 = dpp_xor8(u2);      // side receives act's u2
  float t3 = dpp_xor8(u3);
  float base0 = side ? t2 : u0, add0 = side ? g1[2] : t0;
  float base1 = side ? t3 : u1, add1 = side ? g1[3] : t1;
  out[0] = base0 + add0 * INV2048;
  out[1] = base1 + add1 * INV2048;
}

// d gate: spk cols 8-15 are exactly 0 -> cross terms vanish on both sides.
__device__ __forceinline__ void fold_d(floatx4 g1, floatx4 g2, bool side,
                                       float out[2]) {
  float u0 = g1[0] + g2[0] * INV2048;
  float u1 = g1[1] + g2[1] * INV2048;
  float u2 = g1[2] + g2[2] * INV2048;
  float u3 = g1[3] + g2[3] * INV2048;
  float t2 = dpp_xor8(u2);
  float t3 = dpp_xor8(u3);
  out[0] = side ? t2 : u0;
  out[1] = side ? t3 : u1;
}

// ---- prep: fold dense->tau coupling into f16 hi/lo fragment arrays, plus
// the f32 ext-coefficient table. M/A-gate paths pre-scaled by -log2(e).
__global__ __launch_bounds__(192) void prep(
    const float* __restrict__ W1x, const float* __restrict__ b1x,
    const float* __restrict__ WtauM, const float* __restrict__ btauM,
    const float* __restrict__ WtauAdp, const float* __restrict__ btauAdp,
    _Float16* __restrict__ ws) {
  const int h = blockIdx.x, k = threadIdx.x;
  if (k >= 131) return;
  if (k < 128) {
    float w1 = W1x[h * 130 + 2 + k];
    float s1 = 0.f, s2 = 0.f;
    for (int d = 0; d < 128; ++d) {
      float wd = W1x[d * 130 + 2 + k];
      s1 += WtauM[h * 256 + d] * wd;
      s2 += WtauAdp[h * 256 + d] * wd;
    }
    put_hl(ws, H_M1H, H_M1L, h * 128 + k, w1);
    put_hl(ws, H_MSH, H_MSL, h * 128 + k, s1 * NLOG2E);
    put_hl(ws, H_ASH, H_ASL, h * 128 + k, s2 * NLOG2E);
    put_hl(ws, H_WMH, H_WML, h * 128 + k, WtauM[h * 256 + 128 + k] * NLOG2E);
    put_hl(ws, H_WBH, H_WBL, h * 128 + k, WtauAdp[h * 256 + 128 + k] * NLOG2E);
  } else {
    const int col = k - 128;   // 0: bias, 1: x0-coef, 2: x1-coef
    float m1v = (col == 0) ? b1x[h] : W1x[h * 130 + (col - 1)];
    float sm = 0.f, sa = 0.f;
    for (int d = 0; d < 128; ++d) {
      float cv = (col == 0) ? b1x[d] : W1x[d * 130 + (col - 1)];
      sm += WtauM[h * 256 + d] * cv;
      sa += WtauAdp[h * 256 + d] * cv;
    }
    if (col == 0) { sm += btauM[h]; sa += btauAdp[h]; }
    float* EXTF = (float*)ws + F_EXT;
    EXTF[(0 * 3 + col) * 128 + h] = m1v;
    EXTF[(1 * 3 + col) * 128 + h] = sm * NLOG2E;
    EXTF[(2 * 3 + col) * 128 + h] = sa * NLOG2E;
  }
}

// State slabs. mem/bbp per k-chunk: 1 KB, half-index (q'*16+n')*8+j holds
// B[k=f*32+q'*8+j][n']; n'=0..7 hi, n'=8..15 lo(x2048). spk is PACKED to the
// 8 real cols (spike is exact in f16, no lo) -> 512 B/chunk, fully
// overwritten every step. Side lanes broadcast-read zero16 for S.
struct SLds {
  _Float16 spk[2][4][256];
  _Float16 zero16[8];           // 16 B of zeros, same-address broadcast read
  _Float16 mem[2][4][512];
  _Float16 bbp[2][4][512];
  float red[8][8];
  float red2[8];
};

__global__ __launch_bounds__(512, 2) void snn_main(
    const float* __restrict__ x, const float* __restrict__ y,
    const float* __restrict__ h0m, const float* __restrict__ h0s,
    const float* __restrict__ h0b,
    const float* __restrict__ Wlin, const float* __restrict__ blin,
    const _Float16* __restrict__ W, float* __restrict__ wsout) {
  __shared__ SLds L;

  const int tid  = threadIdx.x;
  const int w    = tid >> 6;      // wave 0..7, owns h-slice [16w, 16w+16)
  const int lane = tid & 63;
  const int c    = lane & 15;     // A-frag m / B-frag n / C col
  const int q    = lane >> 4;
  const int cc   = c & 7;         // batch column within the tile
  const int bbase = blockIdx.x * MTILE;
  const bool act  = (c < 8);
  const bool side = !act;         // side lanes own neurons r=2,3

  // ---- Register-resident A-frag weights (MFMA-only -> AGPR side)
  half8 m1h[4], m1l[4], msh[4], msl[4], ash[4], asl[4];
  half8 wmh[4], wml[4], wbh[4], wbl[4];
  {
    const int hA = w * 16 + c;
#pragma unroll
    for (int f = 0; f < 4; ++f) {
      const int o = hA * 128 + f * 32 + q * 8;
      m1h[f] = *(const half8*)&W[H_M1H + o];
      m1l[f] = *(const half8*)&W[H_M1L + o];
      msh[f] = *(const half8*)&W[H_MSH + o];
      msl[f] = *(const half8*)&W[H_MSL + o];
      ash[f] = *(const half8*)&W[H_ASH + o];
      asl[f] = *(const half8*)&W[H_ASL + o];
      wmh[f] = *(const half8*)&W[H_WMH + o];
      wml[f] = *(const half8*)&W[H_WML + o];
      wbh[f] = *(const half8*)&W[H_WBH + o];
      wbl[f] = *(const half8*)&W[H_WBL + o];
    }
  }

  if (tid == 0) {   // 16 B zero block for c>=8 broadcast S reads
    *(half8*)&L.zero16[0] = half8{0, 0, 0, 0, 0, 0, 0, 0};
  }

  // ---- f32 ext coefficients for this lane's 2 neurons (h0i, h0i+1)
  const int h0i = w * 16 + q * 4 + (side ? 2 : 0);
  const float* CF = (const float*)W + F_EXT;
  floatx2 cd0 = *(const floatx2*)&CF[0 * 128 + h0i];
  floatx2 cd1 = *(const floatx2*)&CF[1 * 128 + h0i];
  floatx2 cd2 = *(const floatx2*)&CF[2 * 128 + h0i];
  floatx2 cm0 = *(const floatx2*)&CF[3 * 128 + h0i];
  floatx2 cm1 = *(const floatx2*)&CF[4 * 128 + h0i];
  floatx2 cm2 = *(const floatx2*)&CF[5 * 128 + h0i];
  floatx2 ca0 = *(const floatx2*)&CF[6 * 128 + h0i];
  floatx2 ca1 = *(const floatx2*)&CF[7 * 128 + h0i];
  floatx2 ca2 = *(const floatx2*)&CF[8 * 128 + h0i];

  // ---- Per-lane recurrent state: EVERY lane owns 2 neurons.
  float memv[2], spk[2], bb[2];
  {
    const int gi = (bbase + cc) * HID + h0i;
    float2 tm = *(const float2*)&h0m[gi];
    float2 ts = *(const float2*)&h0s[gi];
    float2 tb = *(const float2*)&h0b[gi];
    memv[0] = tm.x; memv[1] = tm.y;
    spk[0]  = ts.x; spk[1]  = ts.y;
    bb[0]   = tb.x; bb[1]   = tb.y;
  }

  // State value (h = w*16+q*4+side*2+rr) enters GEMM2 as B[k=h][n]:
  // chunk fW = w>>1, granule qp = (w&1)*2 + (q>>1), j = (q&1)*4 + side*2 + rr.
  const int fW  = w >> 1;
  const int qp  = (w & 1) * 2 + (q >> 1);
  const int jo  = (q & 1) * 4 + (side ? 2 : 0);
  const int wiH = (qp * 16 + cc) * 8 + jo;        // mem/bbp hi (n'=cc)
  const int wiL = wiH + 64;                       // mem/bbp lo (n'=cc+8)
  const int wiS = (qp * 8 + cc) * 8 + jo;         // packed spk
  const int ri  = lane * 8;                       // mem/bbp read (identity)
  const _Float16* spkB0 = act ? &L.spk[0][0][(q * 8 + cc) * 8] : L.zero16;
  const _Float16* spkB1 = act ? &L.spk[1][0][(q * 8 + cc) * 8] : L.zero16;
  const int spkStep = act ? 256 : 0;

  {   // initial state into buf 0 (all lanes, 2 values each)
    half2h ps2, mh2, ml2, bh2, bl2;
#pragma unroll
    for (int rr = 0; rr < 2; ++rr) {
      ps2[rr] = (_Float16)spk[rr];
      float v = memv[rr]; _Float16 hi = (_Float16)v;
      mh2[rr] = hi; ml2[rr] = (_Float16)((v - (float)hi) * 2048.0f);
      v = bb[rr]; hi = (_Float16)v;
      bh2[rr] = hi; bl2[rr] = (_Float16)((v - (float)hi) * 2048.0f);
    }
    *(half2h*)&L.spk[0][fW][wiS] = ps2;
    *(half2h*)&L.mem[0][fW][wiH] = mh2; *(half2h*)&L.mem[0][fW][wiL] = ml2;
    *(half2h*)&L.bbp[0][fW][wiH] = bh2; *(half2h*)&L.bbp[0][fW][wiL] = bl2;
  }
  __syncthreads();

  // Per-lane x stream for batch bbase+cc, prefetched one step ahead.
  const float* xb = x + (size_t)(bbase + cc) * 2;
  float2 xv = *(const float2*)xb;   // x at t=0

#pragma unroll 1
  for (int t = 0; t < S_LEN; ++t) {
    const int p = t & 1, pn = p ^ 1;
    const size_t tn = (t + 1 < S_LEN) ? (size_t)(t + 1) : (size_t)t;
    float2 xnx = *(const float2*)(xb + tn * (size_t)(BATCH * 2));  // prefetch

    const _Float16* sB = p ? spkB1 : spkB0;

    floatx4 d1 = {0.f,0.f,0.f,0.f}, d2 = {0.f,0.f,0.f,0.f};
    floatx4 m1 = {0.f,0.f,0.f,0.f}, m2 = {0.f,0.f,0.f,0.f};
    floatx4 a1 = {0.f,0.f,0.f,0.f}, a2 = {0.f,0.f,0.f,0.f};

#pragma unroll
    for (int f = 0; f < 4; ++f) {
      half8 S = *(const half8*)&sB[f * spkStep];   // [spk] (0 for c>=8)
      half8 M = *(const half8*)&L.mem[p][f][ri];   // [mh  | ml]
      half8 B = *(const half8*)&L.bbp[p][f][ri];   // [bh  | bl]
      d1 = MFMA(m1h[f], S, d1);
      d2 = MFMA(m1l[f], S, d2);
      m1 = MFMA(msh[f], S, m1);
      m1 = MFMA(wmh[f], M, m1);    // cols0-7: wmh*mh ; cols8-15: wmh*ml
      m2 = MFMA(msl[f], S, m2);
      m2 = MFMA(wml[f], M, m2);    // cols0-7: wml*mh ; cols8-15: junk
      a1 = MFMA(ash[f], S, a1);
      a1 = MFMA(wbh[f], B, a1);
      a2 = MFMA(asl[f], S, a2);
      a2 = MFMA(wbl[f], B, a2);
    }

    const float xc0 = xv.x, xc1 = xv.y;

    // M gate first: its exp2 issues while the a/d folds run on the VALU.
    float preM[2], preA[2], den[2];
    fold_u(m1, m2, side, preM);
    float pM0 = preM[0] + cm0[0] + cm1[0] * xc0 + cm2[0] * xc1;
    float pM1 = preM[1] + cm0[1] + cm1[1] * xc0 + cm2[1] * xc1;
    float eM0 = __builtin_amdgcn_exp2f(pM0);   // weights pre-scaled by -log2e
    float eM1 = __builtin_amdgcn_exp2f(pM1);
    fold_u(a1, a2, side, preA);
    float pA0 = preA[0] + ca0[0] + ca1[0] * xc0 + ca2[0] * xc1;
    float pA1 = preA[1] + ca0[1] + ca1[1] * xc0 + ca2[1] * xc1;
    float eA0 = __builtin_amdgcn_exp2f(pA0);
    float eA1 = __builtin_amdgcn_exp2f(pA1);
    fold_d(d1, d2, side, den);

    float tM[2] = { __builtin_amdgcn_rcpf(1.0f + eM0),
                    __builtin_amdgcn_rcpf(1.0f + eM1) };
    float tA[2] = { __builtin_amdgcn_rcpf(1.0f + eA0),
                    __builtin_amdgcn_rcpf(1.0f + eA1) };

    // ---- Elementwise update: 2 real neurons per lane (64 lanes busy).
    half2h ps2, mh2, ml2, bh2, bl2;
#pragma unroll
    for (int rr = 0; rr < 2; ++rr) {
      float dv = den[rr] + cd0[rr] + cd1[rr] * xc0 + cd2[rr] * xc1;
      bb[rr] = tA[rr] * bb[rr] + (1.0f - tA[rr]) * spk[rr];
      float Bth = 0.01f + 1.8f * bb[rr];
      memv[rr] = memv[rr] * tM[rr] + (1.0f - tM[rr]) * dv - Bth * spk[rr];
      spk[rr] = (memv[rr] - Bth) > 0.0f ? 1.0f : 0.0f;
      ps2[rr] = (_Float16)spk[rr];
      float v = bb[rr]; _Float16 hi = (_Float16)v;
      bh2[rr] = hi; bl2[rr] = (_Float16)((v - (float)hi) * 2048.0f);
      v = memv[rr]; hi = (_Float16)v;
      mh2[rr] = hi; ml2[rr] = (_Float16)((v - (float)hi) * 2048.0f);
    }
    // bbp/spk stores first: start the lgkm drain while mem pack retires.
    *(half2h*)&L.bbp[pn][fW][wiH] = bh2; *(half2h*)&L.bbp[pn][fW][wiL] = bl2;
    *(half2h*)&L.spk[pn][fW][wiS] = ps2;
    *(half2h*)&L.mem[pn][fW][wiH] = mh2; *(half2h*)&L.mem[pn][fW][wiL] = ml2;

    xv = xnx;
    __syncthreads();
  }

  // ---- Readout: out[b] = mem[b,:] @ Wlin + blin; per-block loss partial
  float part = memv[0] * Wlin[h0i] + memv[1] * Wlin[h0i + 1];
  part += __shfl_xor(part, 8);    // sum over side
  part += __shfl_xor(part, 16);   // sum over q
  part += __shfl_xor(part, 32);
  if (lane < 8) L.red[w][c] = part;
  __syncthreads();
  if (tid < 8) {
    float s = 0.0f;
#pragma unroll
    for (int ww = 0; ww < 8; ++ww) s += L.red[ww][tid];
    float out = s + blin[0];
    float d = out - y[bbase + tid];
    L.red2[tid] = d * d;
  }
  __syncthreads();
  if (tid == 0) {
    float s = 0.0f;
#pragma unroll
    for (int m = 0; m < MTILE; ++m) s += L.red2[m];
    wsout[blockIdx.x] = s;
  }
}

__global__ __launch_bounds__(256) void final_reduce(const float* __restrict__ part,
                                                    float* __restrict__ out) {
  __shared__ float sh[256];
  int t = threadIdx.x;
  sh[t] = part[t];
  __syncthreads();
  for (int s = 128; s > 0; s >>= 1) {
    if (t < s) sh[t] += sh[t + s];
    __syncthreads();
  }
  if (t == 0) out[0] = sh[0] * (1.0f / (float)BATCH);
}

extern "C" void kernel_launch(void* const* d_in, const int* in_sizes, int n_in,
                              void* d_out, int out_size, void* d_ws, size_t ws_size,
                              hipStream_t stream) {
  const float* x       = (const float*)d_in[0];
  const float* y       = (const float*)d_in[1];
  const float* h0m     = (const float*)d_in[2];
  const float* h0s     = (const float*)d_in[3];
  const float* h0b     = (const float*)d_in[4];
  const float* W1x     = (const float*)d_in[5];
  const float* b1x     = (const float*)d_in[6];
  const float* WtauM   = (const float*)d_in[7];
  const float* btauM   = (const float*)d_in[8];
  const float* WtauAdp = (const float*)d_in[9];
  const float* btauAdp = (const float*)d_in[10];
  const float* Wlin    = (const float*)d_in[11];
  const float* blin    = (const float*)d_in[12];
  _Float16* wsf16 = (_Float16*)d_ws;
  float* wspart = (float*)d_ws + OFF_PART_F;

  prep<<<128, 192, 0, stream>>>(W1x, b1x, WtauM, btauM, WtauAdp, btauAdp, wsf16);
  snn_main<<<NBLK, 512, 0, stream>>>(x, y, h0m, h0s, h0b, Wlin, blin,
                                     wsf16, wspart);
  final_reduce<<<1, 256, 0, stream>>>(wspart, (float*)d_out);
}